// Round 2
// 951.068 us; speedup vs baseline: 1.0143x; 1.0143x over previous
//
#include <hip/hip_runtime.h>

#define TB 512   // batch
#define TT 1024  // time
#define TD 64    // input dim
#define TH 128   // hidden
#define NR 4     // batch rows per block -> 128 blocks, 1 per CU (of 256)

typedef __attribute__((ext_vector_type(8))) short short8;  // 8 bf16 (4 VGPRs)
typedef __attribute__((ext_vector_type(4))) float f32x4;   // MFMA C/D

#define LOG2E 1.44269504f

// fp32 -> bf16 bits, round-to-nearest-even
__device__ __forceinline__ short bfb(float f) {
    unsigned u = __builtin_bit_cast(unsigned, f);
    u = (u + 0x7FFFu + ((u >> 16) & 1u)) >> 16;
    return (short)u;
}

// Barrier with LDS-only drain: global loads/stores stay in flight across it.
#define BAR() asm volatile("s_waitcnt lgkmcnt(0)\n\ts_barrier" ::: "memory")
// compiler-only ordering fence (intra-wave DS write -> read; HW DS pipe is
// in-order per wave, we only need to stop compiler reordering)
#define WAVE_FENCE() asm volatile("" ::: "memory")

#define MFMA(a, b, cc) __builtin_amdgcn_mfma_f32_16x16x32_bf16(a, b, cc, 0, 0, 0)

// ---------------- phase 1: x -> bf16 A-fragment order (compact, 4 rows) -----
// ws layout (short8 units): [blk 0..127][t][kt 0..1][e 0..15], e = c*4 + quad
// holds x[blk*4 + c][t][32*kt + 8*quad + j], j=0..7
__global__ __launch_bounds__(256)
void xswz(const float* __restrict__ x, short8* __restrict__ ws) {
    int gid = blockIdx.x * 256 + threadIdx.x;   // 128*1024*2*16 = 4.19M
    int e   = gid & 15;
    int kt  = (gid >> 4) & 1;
    int t   = (gid >> 5) & (TT - 1);
    int blk = gid >> 15;
    int c = e >> 2, quad = e & 3;
    const float* p = x + ((size_t)(blk * NR + c) * TT + t) * TD + 32 * kt + 8 * quad;
    f32x4 a = *(const f32x4*)p;
    f32x4 b = *(const f32x4*)(p + 4);
    short8 f;
    #pragma unroll
    for (int j = 0; j < 4; ++j) { f[j] = bfb(a[j]); f[4 + j] = bfb(b[j]); }
    ws[gid] = f;
}

// ---------------- phase 2: the scan -----------------------------------------
// 128 blocks x 512 threads. Block owns 4 batch rows (MFMA rows 4..15 zero).
// Wave w owns gate cols {16w+c, +128, +256}. Post-barrier critical path is
// h-MFMAs only (2-deep chains): x-gate accumulators for step t+1 are computed
// during step t and carried across the barrier in registers. The C-layout
// redistribution uses the known-correct intra-wave LDS exchange (same-wave DS
// ops are pipe-ordered; no barrier). The anx exchange value is available from
// the previous step, so its DS write issues immediately after the barrier.
template <bool USE_WS>
__global__ __launch_bounds__(512, 1)
void gru_mfma(const float* __restrict__ x, const short8* __restrict__ xw,
              const float* __restrict__ mask,
              const float* __restrict__ w_ih, const float* __restrict__ w_hh,
              const float* __restrict__ b_ih, const float* __restrict__ b_hh,
              const float* __restrict__ Wo, const float* __restrict__ bo,
              float* __restrict__ out)
{
    __shared__ short hbuf[2][16][136];    // h(t) bf16 A-frag; rows 4..15 stay 0
    __shared__ float exws[8][4][16][4];   // per-wave acc exchange (8 KB)
    __shared__ float mlds[TT][NR];        // mask slice (16 KB)

    const int tid  = threadIdx.x;
    const int w    = tid >> 6;
    const int lane = tid & 63;
    const int c    = lane & 15;
    const int quad = lane >> 4;
    const int Bb   = blockIdx.x * NR;

    // ---- one-time staging ----
    for (int i = tid; i < TT * NR; i += 512) {
        int t = i >> 2, b = i & 3;
        mlds[t][b] = mask[(size_t)(Bb + b) * TT + t];
    }
    for (int i = tid; i < 2 * 16 * 136; i += 512) (&hbuf[0][0][0])[i] = 0;

    const int jj = 16 * w + c;            // gate column this lane owns

    // ---- weights -> bf16 B-fragments in registers ----
    short8 whh[3][4], wih[3][2], wof[4];
    {
        const int gg[3] = {jj, TH + jj, 2 * TH + jj};
        #pragma unroll
        for (int g = 0; g < 3; ++g) {
            #pragma unroll
            for (int kt = 0; kt < 4; ++kt) {
                const float* p = w_hh + (size_t)gg[g] * TH + 32 * kt + 8 * quad;
                short8 f;
                #pragma unroll
                for (int j = 0; j < 8; ++j) f[j] = bfb(p[j]);
                whh[g][kt] = f;
            }
            #pragma unroll
            for (int kt = 0; kt < 2; ++kt) {
                const float* p = w_ih + (size_t)gg[g] * TD + 32 * kt + 8 * quad;
                short8 f;
                #pragma unroll
                for (int j = 0; j < 8; ++j) f[j] = bfb(p[j]);
                wih[g][kt] = f;
            }
        }
        #pragma unroll
        for (int kt = 0; kt < 4; ++kt) {
            short8 f = {0,0,0,0,0,0,0,0};
            if (c < 2) {
                const float* p = Wo + (size_t)c * TH + 32 * kt + 8 * quad;
                #pragma unroll
                for (int j = 0; j < 8; ++j) f[j] = bfb(p[j]);
            }
            wof[kt] = f;
        }
    }

    // epilogue constants for col jj (same for all 4 rows)
    const float crK = -LOG2E * (b_ih[jj] + b_hh[jj]);
    const float czK = -LOG2E * (b_ih[TH + jj] + b_hh[TH + jj]);
    const float bin = b_ih[2 * TH + jj];
    const float bhn = b_hh[2 * TH + jj];
    const float boc = (c < 2) ? bo[c] : 0.0f;

    const short8 z8  = {0,0,0,0,0,0,0,0};
    const f32x4  zf4 = {0.f, 0.f, 0.f, 0.f};

    // x access bases
    const short8* xwp  = xw + (size_t)blockIdx.x * (TT * 32) + (c * 4 + quad);
    const float*  xrow = x + (size_t)(Bb + (c < 4 ? c : 0)) * TT * TD + 8 * quad;

    short8 xf0[2], xf1[2];
    // frags(0) -> xf0
    if (USE_WS) {
        xf0[0] = (c < 4) ? xwp[0]  : z8;
        xf0[1] = (c < 4) ? xwp[16] : z8;
    } else {
        #pragma unroll
        for (int kt = 0; kt < 2; ++kt) {
            f32x4 a = *(const f32x4*)(xrow + 32 * kt);
            f32x4 b = *(const f32x4*)(xrow + 32 * kt + 4);
            short8 f = z8;
            if (c < 4) {
                #pragma unroll
                for (int j = 0; j < 4; ++j) { f[j] = bfb(a[j]); f[4 + j] = bfb(b[j]); }
            }
            xf0[kt] = f;
        }
    }

    // xacc(0) from frags(0)
    f32x4 xacA[3], xacB[3];
    #pragma unroll
    for (int g = 0; g < 3; ++g) {
        f32x4 a = zf4;
        a = MFMA(xf0[0], wih[g][0], a);
        a = MFMA(xf0[1], wih[g][1], a);
        xacA[g] = a;
    }

    // frags(1) -> xf0 (regs free again; xacc(0) extracted)
    if (USE_WS) {
        xf0[0] = (c < 4) ? xwp[32] : z8;
        xf0[1] = (c < 4) ? xwp[48] : z8;
    } else {
        const float* p = xrow + (size_t)1 * TD;
        #pragma unroll
        for (int kt = 0; kt < 2; ++kt) {
            f32x4 a = *(const f32x4*)(p + 32 * kt);
            f32x4 b = *(const f32x4*)(p + 32 * kt + 4);
            short8 f = z8;
            if (c < 4) {
                #pragma unroll
                for (int j = 0; j < 4; ++j) { f[j] = bfb(a[j]); f[4 + j] = bfb(b[j]); }
            }
            xf0[kt] = f;
        }
    }

    float hold = 0.0f;                    // fp32 h for (row=quad, col=jj)

// Invariants entering STEP(t): AC = xacc(t); XC = frags(t+1) (in flight).
// STEP(t) issues loads for frags(t+2) into XN and builds AN = xacc(t+1).
#define STEP(T, XC, XN, AC, AN)                                                 \
  {                                                                             \
    const int t = (T);                                                          \
    BAR();                                                                      \
    const int rb = t & 1, wb = rb ^ 1;                                          \
    short8 ha[4];                                                               \
    _Pragma("unroll")                                                           \
    for (int kt = 0; kt < 4; ++kt)                                              \
        ha[kt] = *(const short8*)(&hbuf[rb][c][32 * kt + 8 * quad]);            \
    const float m = mlds[t][quad];        /* issued early, hides under MFMAs */ \
    /* anx is ready from the previous step: write it to exws immediately */     \
    if (quad == 0) *(f32x4*)(&exws[w][3][c][0]) = AC[2];                        \
    const int tn = (t + 2 < TT) ? t + 2 : TT - 1;                               \
    f32x4 nxa0, nxb0, nxa1, nxb1;                                               \
    if (USE_WS) {                                                               \
        XN[0] = (c < 4) ? xwp[(size_t)tn * 32]      : z8;                       \
        XN[1] = (c < 4) ? xwp[(size_t)tn * 32 + 16] : z8;                       \
    } else {                                                                    \
        const float* p = xrow + (size_t)tn * TD;                                \
        nxa0 = *(const f32x4*)(p);      nxb0 = *(const f32x4*)(p + 4);          \
        nxa1 = *(const f32x4*)(p + 32); nxb1 = *(const f32x4*)(p + 36);         \
    }                                                                           \
    /* h-MFMAs: two 2-deep chains per gate (A: kt0,1 onto xacc; B: kt2,3) */    \
    f32x4 rA = AC[0], zA = AC[1], nA = zf4;                                     \
    f32x4 rB = zf4, zB = zf4, nB = zf4;                                         \
    rA = MFMA(ha[0], whh[0][0], rA);                                            \
    zA = MFMA(ha[0], whh[1][0], zA);                                            \
    nA = MFMA(ha[0], whh[2][0], nA);                                            \
    rB = MFMA(ha[2], whh[0][2], rB);                                            \
    zB = MFMA(ha[2], whh[1][2], zB);                                            \
    nB = MFMA(ha[2], whh[2][2], nB);                                            \
    rA = MFMA(ha[1], whh[0][1], rA);                                            \
    zA = MFMA(ha[1], whh[1][1], zA);                                            \
    nA = MFMA(ha[1], whh[2][1], nA);                                            \
    rB = MFMA(ha[3], whh[0][3], rB);                                            \
    zB = MFMA(ha[3], whh[1][3], zB);                                            \
    nB = MFMA(ha[3], whh[2][3], nB);                                            \
    /* combine + exchange write (quad0 lanes hold rows 0..3) */                 \
    {                                                                           \
        f32x4 arV = rA + rB, azV = zA + zB, anhV = nA + nB;                     \
        if (quad == 0) {                                                        \
            *(f32x4*)(&exws[w][0][c][0]) = arV;                                 \
            *(f32x4*)(&exws[w][1][c][0]) = azV;                                 \
            *(f32x4*)(&exws[w][2][c][0]) = anhV;                                \
        }                                                                       \
    }                                                                           \
    /* logits for t-1 (rotating wave) — MFMA pipe, overlaps DS latency */       \
    if (t > 0 && w == ((t - 1) & 7)) {                                          \
        f32x4 lacc = zf4;                                                       \
        _Pragma("unroll")                                                       \
        for (int kt = 0; kt < 4; ++kt) lacc = MFMA(ha[kt], wof[kt], lacc);      \
        if (c < 2 && quad == 0) {                                               \
            _Pragma("unroll")                                                   \
            for (int i = 0; i < 4; ++i)                                         \
                out[((size_t)(Bb + i) * TT + (t - 1)) * 2 + c] = lacc[i] + boc; \
        }                                                                       \
    }                                                                           \
    /* next step's x-gate accumulators — also overlaps the DS round-trip */     \
    _Pragma("unroll")                                                           \
    for (int g = 0; g < 3; ++g) {                                               \
        f32x4 a = zf4;                                                          \
        a = MFMA(XC[0], wih[g][0], a);                                          \
        a = MFMA(XC[1], wih[g][1], a);                                          \
        AN[g] = a;                                                              \
    }                                                                           \
    WAVE_FENCE();                                                               \
    {                                                                           \
        float arS  = exws[w][0][c][quad];                                       \
        float azS  = exws[w][1][c][quad];                                       \
        float anhS = exws[w][2][c][quad];                                       \
        float anxS = exws[w][3][c][quad];                                       \
        float er = __builtin_amdgcn_exp2f(__builtin_fmaf(arS, -LOG2E, crK));    \
        float r  = __builtin_amdgcn_rcpf(1.0f + er);                            \
        float ez = __builtin_amdgcn_exp2f(__builtin_fmaf(azS, -LOG2E, czK));    \
        float z  = __builtin_amdgcn_rcpf(1.0f + ez);                            \
        float pp = (anxS + bin) + r * (anhS + bhn);                             \
        float e2 = __builtin_amdgcn_exp2f(pp * (2.0f * LOG2E));                 \
        float n  = __builtin_fmaf(-2.0f, __builtin_amdgcn_rcpf(1.0f + e2), 1.0f); \
        float hn = n + z * (hold - n);                                          \
        hold = hold + m * (hn - hold);                                          \
        hbuf[wb][quad][jj] = bfb(hold);                                         \
    }                                                                           \
    if (!USE_WS) {                                                              \
        short8 f0 = z8, f1 = z8;                                                \
        if (c < 4) {                                                            \
            _Pragma("unroll")                                                   \
            for (int j = 0; j < 4; ++j) { f0[j] = bfb(nxa0[j]); f0[4+j] = bfb(nxb0[j]); \
                                          f1[j] = bfb(nxa1[j]); f1[4+j] = bfb(nxb1[j]); } \
        }                                                                       \
        XN[0] = f0; XN[1] = f1;                                                 \
    }                                                                           \
  }

    for (int t2 = 0; t2 < TT; t2 += 2) {
        STEP(t2,     xf0, xf1, xacA, xacB);
        STEP(t2 + 1, xf1, xf0, xacB, xacA);
    }
#undef STEP

    // flush logits for t = TT-1 (h(TT-1) sits in hbuf[0])
    BAR();
    if (w == 7) {
        short8 ha[4];
        #pragma unroll
        for (int kt = 0; kt < 4; ++kt)
            ha[kt] = *(const short8*)(&hbuf[0][c][32 * kt + 8 * quad]);
        f32x4 lacc = zf4;
        #pragma unroll
        for (int kt = 0; kt < 4; ++kt) lacc = MFMA(ha[kt], wof[kt], lacc);
        if (c < 2 && quad == 0) {
            #pragma unroll
            for (int i = 0; i < 4; ++i)
                out[((size_t)(Bb + i) * TT + (TT - 1)) * 2 + c] = lacc[i] + boc;
        }
    }
}

extern "C" void kernel_launch(void* const* d_in, const int* in_sizes, int n_in,
                              void* d_out, int out_size, void* d_ws, size_t ws_size,
                              hipStream_t stream) {
    const float* x    = (const float*)d_in[0];
    const float* mask = (const float*)d_in[1];
    const float* w_ih = (const float*)d_in[2];
    const float* w_hh = (const float*)d_in[3];
    const float* b_ih = (const float*)d_in[4];
    const float* b_hh = (const float*)d_in[5];
    const float* Wo   = (const float*)d_in[6];
    const float* bo   = (const float*)d_in[7];
    float* out = (float*)d_out;
    (void)in_sizes; (void)n_in; (void)out_size;

    const size_t nfrag = (size_t)(TB / NR) * TT * 2 * 16;       // 4.19M short8
    const size_t need  = nfrag * sizeof(short8);                // 67.1 MB
    if (ws_size >= need) {
        short8* xw = (short8*)d_ws;
        xswz<<<(int)(nfrag / 256), 256, 0, stream>>>(x, xw);
        gru_mfma<true><<<TB / NR, 512, 0, stream>>>(x, xw, mask, w_ih, w_hh,
                                                    b_ih, b_hh, Wo, bo, out);
    } else {
        gru_mfma<false><<<TB / NR, 512, 0, stream>>>(x, (const short8*)nullptr, mask,
                                                     w_ih, w_hh, b_ih, b_hh, Wo, bo, out);
    }
}